// Round 1
// baseline (923.123 us; speedup 1.0000x reference)
//
#include <hip/hip_runtime.h>
#include <hip/hip_bf16.h>

#define N_NODES 50000
#define N_EDGES 800000

typedef __bf16 bf16x8 __attribute__((ext_vector_type(8)));
typedef float f32x4 __attribute__((ext_vector_type(4)));

__device__ __forceinline__ unsigned short f2bf(float f) {
    unsigned int u = __builtin_bit_cast(unsigned int, f);
    u += 0x7fffu + ((u >> 16) & 1u);   // round-to-nearest-even
    return (unsigned short)(u >> 16);
}

// ---------------- degree count: deg[col] += 1 ----------------
__global__ void k_deg(const int* __restrict__ ei, int* __restrict__ deg) {
    int e = blockIdx.x * 256 + threadIdx.x;           // grid sized exactly E
    atomicAdd(&deg[ei[N_EDGES + e]], 1);
}

// ---------------- vbar GEMM ----------------
// vbar[n,d] = sum_c Xs[n,c] * Wvbar[d,c] + bvbar[d]
// Wvbar[d,c] = 0.25 * sum_h Wv[h*64+d, c]  (head-mean folded into weights)
// also accumulates ss[c] = sum_n Xs[n,c] (fp32, from L2-hot data)
__global__ __launch_bounds__(256, 2) void k_vbar(
    const float* __restrict__ Xs, const float* __restrict__ Wv,
    const float* __restrict__ bv, float* __restrict__ vbar,
    float* __restrict__ ss)
{
    __shared__ unsigned short lA[128 * 40];   // 128 rows x 32 k, stride 40 (pad)
    __shared__ unsigned short lB[64 * 264];   // 64 d-rows x 256 k, stride 264 (pad)
    const int t = threadIdx.x;
    const int n0 = blockIdx.x * 128;
    const int wave = t >> 6;
    const int l = t & 63;
    const int ln = l & 15;
    const int q = l >> 4;

    // --- B preload once: head-averaged Wv -> bf16 LDS ---
    {
        const int d = t >> 2;
        const int cb = (t & 3) * 64;
        const float4* W4 = (const float4*)Wv;
        #pragma unroll 4
        for (int i = 0; i < 16; ++i) {
            int c4 = (cb >> 2) + i;
            float4 w0 = W4[(d) * 64 + c4];
            float4 w1 = W4[(64 + d) * 64 + c4];
            float4 w2 = W4[(128 + d) * 64 + c4];
            float4 w3 = W4[(192 + d) * 64 + c4];
            ushort4 s;
            s.x = f2bf(0.25f * (w0.x + w1.x + w2.x + w3.x));
            s.y = f2bf(0.25f * (w0.y + w1.y + w2.y + w3.y));
            s.z = f2bf(0.25f * (w0.z + w1.z + w2.z + w3.z));
            s.w = f2bf(0.25f * (w0.w + w1.w + w2.w + w3.w));
            *(ushort4*)&lB[d * 264 + cb + i * 4] = s;
        }
    }

    f32x4 acc[2][4];
    #pragma unroll
    for (int i = 0; i < 2; ++i)
        #pragma unroll
        for (int j = 0; j < 4; ++j)
            acc[i][j] = (f32x4){0.f, 0.f, 0.f, 0.f};

    const int r = t >> 1;
    const int ch = (t & 1) * 16;
    const int gr = n0 + r;
    const float4* X4 = (const float4*)Xs;

    for (int ks = 0; ks < 8; ++ks) {
        __syncthreads();
        {   // stage A: 128 rows x 32 c, fp32 -> bf16
            ushort4 s[4];
            if (gr < N_NODES) {
                #pragma unroll
                for (int i = 0; i < 4; ++i) {
                    float4 x = X4[gr * 64 + ks * 8 + (ch >> 2) + i];
                    s[i].x = f2bf(x.x); s[i].y = f2bf(x.y);
                    s[i].z = f2bf(x.z); s[i].w = f2bf(x.w);
                }
            } else {
                #pragma unroll
                for (int i = 0; i < 4; ++i) s[i] = (ushort4){0, 0, 0, 0};
            }
            #pragma unroll
            for (int i = 0; i < 4; ++i)
                *(ushort4*)&lA[r * 40 + ch + i * 4] = s[i];
        }
        __syncthreads();

        // A-frag: lane holds A[m=ln][k=q*8+j]; B-frag: B[k=q*8+j][n=ln] = Wvbar[ln][k]
        bf16x8 a0 = *(const bf16x8*)&lA[(wave * 32 + ln) * 40 + q * 8];
        bf16x8 a1 = *(const bf16x8*)&lA[(wave * 32 + 16 + ln) * 40 + q * 8];
        #pragma unroll
        for (int nf = 0; nf < 4; ++nf) {
            bf16x8 b = *(const bf16x8*)&lB[(nf * 16 + ln) * 264 + ks * 32 + q * 8];
            acc[0][nf] = __builtin_amdgcn_mfma_f32_16x16x32_bf16(a0, b, acc[0][nf], 0, 0, 0);
            acc[1][nf] = __builtin_amdgcn_mfma_f32_16x16x32_bf16(a1, b, acc[1][nf], 0, 0, 0);
        }
    }

    // epilogue: D[m = q*4+reg][n = ln] per frag; add head-mean bias
    float bvb[4];
    #pragma unroll
    for (int nf = 0; nf < 4; ++nf) {
        int c = nf * 16 + ln;
        bvb[nf] = 0.25f * (bv[c] + bv[64 + c] + bv[128 + c] + bv[192 + c]);
    }
    #pragma unroll
    for (int mf = 0; mf < 2; ++mf) {
        #pragma unroll
        for (int r4 = 0; r4 < 4; ++r4) {
            int m = wave * 32 + mf * 16 + q * 4 + r4;
            int g = n0 + m;
            if (g < N_NODES) {
                #pragma unroll
                for (int nf = 0; nf < 4; ++nf)
                    vbar[g * 64 + nf * 16 + ln] = acc[mf][nf][r4] + bvb[nf];
            }
        }
    }

    // fp32 column sums of this block's rows (L2-hot re-read) -> ss
    {
        float sum = 0.f;
        #pragma unroll 8
        for (int rr = 0; rr < 128; ++rr) {
            int g = n0 + rr;
            if (g < N_NODES) sum += Xs[g * 256 + t];
        }
        atomicAdd(&ss[t], sum);
    }
}

// ---------------- attention constant: a[d] = 0.25/N * sum_h v_sum[h*64+d]
// v_sum[j] = Wv[j,:].ss + N*bv[j]
__global__ void k_scalar(const float* __restrict__ Wv, const float* __restrict__ bv,
                         const float* __restrict__ ss, float* __restrict__ aout)
{
    __shared__ float dot[256];
    __shared__ float s_ss[256];
    int t = threadIdx.x;
    s_ss[t] = ss[t];
    __syncthreads();
    float s = (float)N_NODES * bv[t];
    #pragma unroll 8
    for (int c = 0; c < 256; ++c) s += Wv[t * 256 + c] * s_ss[c];
    dot[t] = s;
    __syncthreads();
    if (t < 64) {
        aout[t] = 0.25f * (dot[t] + dot[64 + t] + dot[128 + t] + dot[192 + t])
                  / (float)N_NODES;
    }
}

// ---------------- out init: out[n,d] = a[d] ----------------
__global__ void k_init(const float* __restrict__ aout, float* __restrict__ out) {
    int i = blockIdx.x * 256 + threadIdx.x;   // float4 index, grid sized exactly
    const float4* a4 = (const float4*)aout;
    ((float4*)out)[i] = a4[i & 15];
}

// ---------------- GCN scatter: out[col,:] += val * vbar[row,:] ----------------
__global__ __launch_bounds__(256) void k_scatter(
    const int* __restrict__ ei, const float* __restrict__ ew,
    const int* __restrict__ deg, const float* __restrict__ vbar,
    float* __restrict__ out)
{
    int t = threadIdx.x;
    int e = blockIdx.x * 16 + (t >> 4);       // 16 edges per block, exact grid
    int sub = t & 15;                          // 16 lanes x float4 = 64 floats
    int row = ei[e];
    int col = ei[N_EDGES + e];
    float w = ew[e];
    int dr = deg[row];
    int dc = deg[col];
    float val = 0.f;
    if (dr > 0) val = w * rsqrtf((float)dr * (float)dc);  // d[row]==0 -> nan_to_num -> 0
    float4 v = ((const float4*)vbar)[row * 16 + sub];
    float* o = out + col * 64 + sub * 4;
    atomicAdd(o + 0, val * v.x);
    atomicAdd(o + 1, val * v.y);
    atomicAdd(o + 2, val * v.z);
    atomicAdd(o + 3, val * v.w);
}

extern "C" void kernel_launch(void* const* d_in, const int* in_sizes, int n_in,
                              void* d_out, int out_size, void* d_ws, size_t ws_size,
                              hipStream_t stream)
{
    const float* Xs = (const float*)d_in[1];   // source_input [N,256]
    const float* Wv = (const float*)d_in[6];   // Wv_w [256,256]
    const float* bv = (const float*)d_in[7];   // Wv_b [256]
    const int*   ei = (const int*)d_in[8];     // edge_index [2,E]
    const float* ew = (const float*)d_in[9];   // edge_weight [E]
    float* out = (float*)d_out;                // [N,64]

    float* vbar = (float*)d_ws;                       // 3.2M floats (12.8 MB)
    int*   deg  = (int*)(vbar + (size_t)N_NODES * 64);// 50000 ints
    float* ss   = (float*)(deg + N_NODES);            // 256 floats
    float* aout = ss + 256;                           // 64 floats

    hipMemsetAsync(deg, 0, (size_t)(N_NODES + 256 + 64) * 4, stream);
    k_deg<<<N_EDGES / 256, 256, 0, stream>>>(ei, deg);
    k_vbar<<<(N_NODES + 127) / 128, 256, 0, stream>>>(Xs, Wv, bv, vbar, ss);
    k_scalar<<<1, 256, 0, stream>>>(Wv, bv, ss, aout);
    k_init<<<(N_NODES * 16) / 256, 256, 0, stream>>>(aout, out);
    k_scatter<<<N_EDGES / 16, 256, 0, stream>>>(ei, ew, deg, vbar, out);
}

// Round 2
// 462.103 us; speedup vs baseline: 1.9977x; 1.9977x over previous
//
#include <hip/hip_runtime.h>
#include <hip/hip_bf16.h>

#define N_NODES 50000
#define N_EDGES 800000

typedef __bf16 bf16x8 __attribute__((ext_vector_type(8)));
typedef float f32x4 __attribute__((ext_vector_type(4)));

__device__ __forceinline__ unsigned short f2bf(float f) {
    unsigned int u = __builtin_bit_cast(unsigned int, f);
    u += 0x7fffu + ((u >> 16) & 1u);   // round-to-nearest-even
    return (unsigned short)(u >> 16);
}

// ---------------- degree count: deg[col] += 1 ----------------
__global__ void k_deg(const int* __restrict__ ei, int* __restrict__ deg) {
    int e = blockIdx.x * 256 + threadIdx.x;           // grid sized exactly E
    atomicAdd(&deg[ei[N_EDGES + e]], 1);
}

// ---------------- exclusive prefix sum of deg -> off, cursor ----------------
// single block, 1024 threads, chunk of 49 nodes each (1024*49 = 50176 >= N)
__global__ __launch_bounds__(1024) void k_scan(
    const int* __restrict__ deg, int* __restrict__ off, int* __restrict__ cursor)
{
    __shared__ int sums[1024];
    const int t = threadIdx.x;
    const int base = t * 49;
    int s = 0;
    #pragma unroll 7
    for (int i = 0; i < 49; ++i) {
        int g = base + i;
        if (g < N_NODES) s += deg[g];
    }
    sums[t] = s;
    __syncthreads();
    // Hillis-Steele inclusive scan over 1024 partials
    #pragma unroll
    for (int d = 1; d < 1024; d <<= 1) {
        int v = 0;
        if (t >= d) v = sums[t - d];
        __syncthreads();
        if (t >= d) sums[t] += v;
        __syncthreads();
    }
    int run = (t == 0) ? 0 : sums[t - 1];
    for (int i = 0; i < 49; ++i) {
        int g = base + i;
        if (g < N_NODES) {
            off[g] = run;
            cursor[g] = run;
            run += deg[g];
        }
    }
    if (t == 1023) off[N_NODES] = run;   // == E
}

// ---------------- counting sort by col: srt[pos] = (row, val) ----------------
__global__ void k_sort(const int* __restrict__ ei, const float* __restrict__ ew,
                       const int* __restrict__ deg, int* __restrict__ cursor,
                       float2* __restrict__ srt)
{
    int e = blockIdx.x * 256 + threadIdx.x;           // grid sized exactly E
    int row = ei[e];
    int col = ei[N_EDGES + e];
    float w = ew[e];
    int dr = deg[row];
    int dc = deg[col];
    float val = 0.f;
    if (dr > 0) val = w * rsqrtf((float)dr * (float)dc);  // deg[row]==0 -> nan_to_num -> 0
    int pos = atomicAdd(&cursor[col], 1);
    float2 rv;
    rv.x = __int_as_float(row);
    rv.y = val;
    srt[pos] = rv;
}

// ---------------- vbar GEMM ----------------
// vbar[n,d] = sum_c Xs[n,c] * Wvbar[d,c] + bvbar[d]
// Wvbar[d,c] = 0.25 * sum_h Wv[h*64+d, c]  (head-mean folded into weights)
// also accumulates ss[c] = sum_n Xs[n,c] (fp32, from L2-hot data)
__global__ __launch_bounds__(256, 2) void k_vbar(
    const float* __restrict__ Xs, const float* __restrict__ Wv,
    const float* __restrict__ bv, float* __restrict__ vbar,
    float* __restrict__ ss)
{
    __shared__ unsigned short lA[128 * 40];   // 128 rows x 32 k, stride 40 (pad)
    __shared__ unsigned short lB[64 * 264];   // 64 d-rows x 256 k, stride 264 (pad)
    const int t = threadIdx.x;
    const int n0 = blockIdx.x * 128;
    const int wave = t >> 6;
    const int l = t & 63;
    const int ln = l & 15;
    const int q = l >> 4;

    // --- B preload once: head-averaged Wv -> bf16 LDS ---
    {
        const int d = t >> 2;
        const int cb = (t & 3) * 64;
        const float4* W4 = (const float4*)Wv;
        #pragma unroll 4
        for (int i = 0; i < 16; ++i) {
            int c4 = (cb >> 2) + i;
            float4 w0 = W4[(d) * 64 + c4];
            float4 w1 = W4[(64 + d) * 64 + c4];
            float4 w2 = W4[(128 + d) * 64 + c4];
            float4 w3 = W4[(192 + d) * 64 + c4];
            ushort4 s;
            s.x = f2bf(0.25f * (w0.x + w1.x + w2.x + w3.x));
            s.y = f2bf(0.25f * (w0.y + w1.y + w2.y + w3.y));
            s.z = f2bf(0.25f * (w0.z + w1.z + w2.z + w3.z));
            s.w = f2bf(0.25f * (w0.w + w1.w + w2.w + w3.w));
            *(ushort4*)&lB[d * 264 + cb + i * 4] = s;
        }
    }

    f32x4 acc[2][4];
    #pragma unroll
    for (int i = 0; i < 2; ++i)
        #pragma unroll
        for (int j = 0; j < 4; ++j)
            acc[i][j] = (f32x4){0.f, 0.f, 0.f, 0.f};

    const int r = t >> 1;
    const int ch = (t & 1) * 16;
    const int gr = n0 + r;
    const float4* X4 = (const float4*)Xs;

    for (int ks = 0; ks < 8; ++ks) {
        __syncthreads();
        {   // stage A: 128 rows x 32 c, fp32 -> bf16
            ushort4 s[4];
            if (gr < N_NODES) {
                #pragma unroll
                for (int i = 0; i < 4; ++i) {
                    float4 x = X4[gr * 64 + ks * 8 + (ch >> 2) + i];
                    s[i].x = f2bf(x.x); s[i].y = f2bf(x.y);
                    s[i].z = f2bf(x.z); s[i].w = f2bf(x.w);
                }
            } else {
                #pragma unroll
                for (int i = 0; i < 4; ++i) s[i] = (ushort4){0, 0, 0, 0};
            }
            #pragma unroll
            for (int i = 0; i < 4; ++i)
                *(ushort4*)&lA[r * 40 + ch + i * 4] = s[i];
        }
        __syncthreads();

        // A-frag: lane holds A[m=ln][k=q*8+j]; B-frag: B[k=q*8+j][n=ln] = Wvbar[ln][k]
        bf16x8 a0 = *(const bf16x8*)&lA[(wave * 32 + ln) * 40 + q * 8];
        bf16x8 a1 = *(const bf16x8*)&lA[(wave * 32 + 16 + ln) * 40 + q * 8];
        #pragma unroll
        for (int nf = 0; nf < 4; ++nf) {
            bf16x8 b = *(const bf16x8*)&lB[(nf * 16 + ln) * 264 + ks * 32 + q * 8];
            acc[0][nf] = __builtin_amdgcn_mfma_f32_16x16x32_bf16(a0, b, acc[0][nf], 0, 0, 0);
            acc[1][nf] = __builtin_amdgcn_mfma_f32_16x16x32_bf16(a1, b, acc[1][nf], 0, 0, 0);
        }
    }

    // epilogue: D[m = q*4+reg][n = ln] per frag; add head-mean bias
    float bvb[4];
    #pragma unroll
    for (int nf = 0; nf < 4; ++nf) {
        int c = nf * 16 + ln;
        bvb[nf] = 0.25f * (bv[c] + bv[64 + c] + bv[128 + c] + bv[192 + c]);
    }
    #pragma unroll
    for (int mf = 0; mf < 2; ++mf) {
        #pragma unroll
        for (int r4 = 0; r4 < 4; ++r4) {
            int m = wave * 32 + mf * 16 + q * 4 + r4;
            int g = n0 + m;
            if (g < N_NODES) {
                #pragma unroll
                for (int nf = 0; nf < 4; ++nf)
                    vbar[g * 64 + nf * 16 + ln] = acc[mf][nf][r4] + bvb[nf];
            }
        }
    }

    // fp32 column sums of this block's rows (L2-hot re-read) -> ss
    {
        float sum = 0.f;
        #pragma unroll 8
        for (int rr = 0; rr < 128; ++rr) {
            int g = n0 + rr;
            if (g < N_NODES) sum += Xs[g * 256 + t];
        }
        atomicAdd(&ss[t], sum);
    }
}

// ---------------- attention constant: a[d] = 0.25/N * sum_h v_sum[h*64+d]
// v_sum[j] = Wv[j,:].ss + N*bv[j]
__global__ void k_scalar(const float* __restrict__ Wv, const float* __restrict__ bv,
                         const float* __restrict__ ss, float* __restrict__ aout)
{
    __shared__ float dot[256];
    __shared__ float s_ss[256];
    int t = threadIdx.x;
    s_ss[t] = ss[t];
    __syncthreads();
    float s = (float)N_NODES * bv[t];
    #pragma unroll 8
    for (int c = 0; c < 256; ++c) s += Wv[t * 256 + c] * s_ss[c];
    dot[t] = s;
    __syncthreads();
    if (t < 64) {
        aout[t] = 0.25f * (dot[t] + dot[64 + t] + dot[128 + t] + dot[192 + t])
                  / (float)N_NODES;
    }
}

// ---------------- GCN gather: one wave per node, lane = d-channel ----------------
// out[n,d] = aconst[d] + sum_{e in [off[n],off[n+1])} srt[e].val * vbar[srt[e].row, d]
__global__ __launch_bounds__(256) void k_gather(
    const int* __restrict__ off, const float2* __restrict__ srt,
    const float* __restrict__ vbar, const float* __restrict__ aout,
    float* __restrict__ out)
{
    const int t = threadIdx.x;
    const int lane = t & 63;
    const int n = blockIdx.x * 4 + (t >> 6);          // grid sized exactly N/4
    const int e0 = off[n];
    const int e1 = off[n + 1];
    float acc = 0.f;
    int e = e0;
    // unroll-by-2 main loop
    for (; e + 1 < e1; e += 2) {
        float2 rv0 = srt[e];
        float2 rv1 = srt[e + 1];
        int r0 = __float_as_int(rv0.x);
        int r1 = __float_as_int(rv1.x);
        acc += rv0.y * vbar[r0 * 64 + lane];
        acc += rv1.y * vbar[r1 * 64 + lane];
    }
    if (e < e1) {
        float2 rv = srt[e];
        int r = __float_as_int(rv.x);
        acc += rv.y * vbar[r * 64 + lane];
    }
    out[n * 64 + lane] = acc + aout[lane];
}

extern "C" void kernel_launch(void* const* d_in, const int* in_sizes, int n_in,
                              void* d_out, int out_size, void* d_ws, size_t ws_size,
                              hipStream_t stream)
{
    const float* Xs = (const float*)d_in[1];   // source_input [N,256]
    const float* Wv = (const float*)d_in[6];   // Wv_w [256,256]
    const float* bv = (const float*)d_in[7];   // Wv_b [256]
    const int*   ei = (const int*)d_in[8];     // edge_index [2,E]
    const float* ew = (const float*)d_in[9];   // edge_weight [E]
    float* out = (float*)d_out;                // [N,64]

    float*  vbar   = (float*)d_ws;                              // 3.2M floats (12.8 MB)
    float2* srt    = (float2*)(vbar + (size_t)N_NODES * 64);    // 800K float2 (6.4 MB)
    int*    deg    = (int*)(srt + N_EDGES);                     // 50000
    int*    off    = deg + N_NODES;                             // 50001
    int*    cursor = off + N_NODES + 1;                         // 50000
    float*  ss     = (float*)(cursor + N_NODES);                // 256
    float*  aout   = ss + 256;                                  // 64

    // zero deg + ss (off/cursor/aout are fully written by kernels)
    hipMemsetAsync(deg, 0, (size_t)(3 * N_NODES + 1 + 256 + 64) * 4, stream);
    k_deg<<<N_EDGES / 256, 256, 0, stream>>>(ei, deg);
    k_vbar<<<(N_NODES + 127) / 128, 256, 0, stream>>>(Xs, Wv, bv, vbar, ss);
    k_scan<<<1, 1024, 0, stream>>>(deg, off, cursor);
    k_sort<<<N_EDGES / 256, 256, 0, stream>>>(ei, ew, deg, cursor, srt);
    k_scalar<<<1, 256, 0, stream>>>(Wv, bv, ss, aout);
    k_gather<<<(N_NODES + 3) / 4, 256, 0, stream>>>(off, srt, vbar, aout, out);
}

// Round 3
// 339.619 us; speedup vs baseline: 2.7181x; 1.3607x over previous
//
#include <hip/hip_runtime.h>
#include <hip/hip_bf16.h>

#define N_NODES 50000
#define N_EDGES 800000
#define NB 196              // scan blocks: 196*256 = 50176 >= N_NODES

typedef __bf16 bf16x8 __attribute__((ext_vector_type(8)));
typedef float f32x4 __attribute__((ext_vector_type(4)));

__device__ __forceinline__ unsigned short f2bf(float f) {
    unsigned int u = __builtin_bit_cast(unsigned int, f);
    u += 0x7fffu + ((u >> 16) & 1u);   // round-to-nearest-even
    return (unsigned short)(u >> 16);
}

// ---------------- degree count: deg[col] += 1 ----------------
__global__ void k_deg(const int* __restrict__ ei, int* __restrict__ deg) {
    int e = blockIdx.x * 256 + threadIdx.x;           // grid sized exactly E
    atomicAdd(&deg[ei[N_EDGES + e]], 1);
}

// ---------------- scan stage 1: per-block sums of deg ----------------
__global__ __launch_bounds__(256) void k_bsum(const int* __restrict__ deg,
                                              int* __restrict__ bsum) {
    __shared__ int ws[4];
    int t = threadIdx.x;
    int g = blockIdx.x * 256 + t;
    int v = (g < N_NODES) ? deg[g] : 0;
    #pragma unroll
    for (int d = 32; d > 0; d >>= 1) v += __shfl_down(v, d, 64);
    if ((t & 63) == 0) ws[t >> 6] = v;
    __syncthreads();
    if (t == 0) bsum[blockIdx.x] = ws[0] + ws[1] + ws[2] + ws[3];
}

// ---------------- scan stage 2: exclusive scan of 196 block sums ----------------
__global__ __launch_bounds__(256) void k_bscan(const int* __restrict__ bsum,
                                               int* __restrict__ boff) {
    __shared__ int s[256];
    int t = threadIdx.x;
    s[t] = (t < NB) ? bsum[t] : 0;
    __syncthreads();
    #pragma unroll
    for (int d = 1; d < 256; d <<= 1) {
        int v = (t >= d) ? s[t - d] : 0;
        __syncthreads();
        if (t >= d) s[t] += v;
        __syncthreads();
    }
    if (t < NB) boff[t] = (t == 0) ? 0 : s[t - 1];
}

// ---------------- scan stage 3: intra-block scan + block offset -> off/cursor ----
__global__ __launch_bounds__(256) void k_off(const int* __restrict__ deg,
                                             const int* __restrict__ boff,
                                             int* __restrict__ off,
                                             int* __restrict__ cursor) {
    __shared__ int s[256];
    int t = threadIdx.x;
    int g = blockIdx.x * 256 + t;
    int d0 = (g < N_NODES) ? deg[g] : 0;
    s[t] = d0;
    __syncthreads();
    #pragma unroll
    for (int d = 1; d < 256; d <<= 1) {
        int v = (t >= d) ? s[t - d] : 0;
        __syncthreads();
        if (t >= d) s[t] += v;
        __syncthreads();
    }
    int excl = boff[blockIdx.x] + ((t == 0) ? 0 : s[t - 1]);
    if (g < N_NODES) { off[g] = excl; cursor[g] = excl; }
    if (g == 0) off[N_NODES] = N_EDGES;   // sum(deg) == E by construction
}

// ---------------- counting sort by col: srt[pos] = (row, val) ----------------
__global__ void k_sort(const int* __restrict__ ei, const float* __restrict__ ew,
                       const int* __restrict__ deg, int* __restrict__ cursor,
                       float2* __restrict__ srt)
{
    int e = blockIdx.x * 256 + threadIdx.x;           // grid sized exactly E
    int row = ei[e];
    int col = ei[N_EDGES + e];
    float w = ew[e];
    int dr = deg[row];
    int dc = deg[col];
    float val = 0.f;
    if (dr > 0) val = w * rsqrtf((float)dr * (float)dc);  // deg[row]==0 -> nan_to_num -> 0
    int pos = atomicAdd(&cursor[col], 1);
    float2 rv;
    rv.x = __int_as_float(row);
    rv.y = val;
    srt[pos] = rv;
}

// ---------------- vbar GEMM ----------------
// vbar[n,d] = sum_c Xs[n,c] * Wvbar[d,c] + bvbar[d]
// Wvbar[d,c] = 0.25 * sum_h Wv[h*64+d, c]  (head-mean folded into weights)
// also accumulates ss[c] = sum_n Xs[n,c] (fp32, from L2-hot data)
__global__ __launch_bounds__(256, 2) void k_vbar(
    const float* __restrict__ Xs, const float* __restrict__ Wv,
    const float* __restrict__ bv, float* __restrict__ vbar,
    float* __restrict__ ss)
{
    __shared__ unsigned short lA[128 * 40];   // 128 rows x 32 k, stride 40 (pad)
    __shared__ unsigned short lB[64 * 264];   // 64 d-rows x 256 k, stride 264 (pad)
    const int t = threadIdx.x;
    const int n0 = blockIdx.x * 128;
    const int wave = t >> 6;
    const int l = t & 63;
    const int ln = l & 15;
    const int q = l >> 4;

    // --- B preload once: head-averaged Wv -> bf16 LDS ---
    {
        const int d = t >> 2;
        const int cb = (t & 3) * 64;
        const float4* W4 = (const float4*)Wv;
        #pragma unroll 4
        for (int i = 0; i < 16; ++i) {
            int c4 = (cb >> 2) + i;
            float4 w0 = W4[(d) * 64 + c4];
            float4 w1 = W4[(64 + d) * 64 + c4];
            float4 w2 = W4[(128 + d) * 64 + c4];
            float4 w3 = W4[(192 + d) * 64 + c4];
            ushort4 s;
            s.x = f2bf(0.25f * (w0.x + w1.x + w2.x + w3.x));
            s.y = f2bf(0.25f * (w0.y + w1.y + w2.y + w3.y));
            s.z = f2bf(0.25f * (w0.z + w1.z + w2.z + w3.z));
            s.w = f2bf(0.25f * (w0.w + w1.w + w2.w + w3.w));
            *(ushort4*)&lB[d * 264 + cb + i * 4] = s;
        }
    }

    f32x4 acc[2][4];
    #pragma unroll
    for (int i = 0; i < 2; ++i)
        #pragma unroll
        for (int j = 0; j < 4; ++j)
            acc[i][j] = (f32x4){0.f, 0.f, 0.f, 0.f};

    const int r = t >> 1;
    const int ch = (t & 1) * 16;
    const int gr = n0 + r;
    const float4* X4 = (const float4*)Xs;

    for (int ks = 0; ks < 8; ++ks) {
        __syncthreads();
        {   // stage A: 128 rows x 32 c, fp32 -> bf16
            ushort4 s[4];
            if (gr < N_NODES) {
                #pragma unroll
                for (int i = 0; i < 4; ++i) {
                    float4 x = X4[gr * 64 + ks * 8 + (ch >> 2) + i];
                    s[i].x = f2bf(x.x); s[i].y = f2bf(x.y);
                    s[i].z = f2bf(x.z); s[i].w = f2bf(x.w);
                }
            } else {
                #pragma unroll
                for (int i = 0; i < 4; ++i) s[i] = (ushort4){0, 0, 0, 0};
            }
            #pragma unroll
            for (int i = 0; i < 4; ++i)
                *(ushort4*)&lA[r * 40 + ch + i * 4] = s[i];
        }
        __syncthreads();

        // A-frag: lane holds A[m=ln][k=q*8+j]; B-frag: B[k=q*8+j][n=ln] = Wvbar[ln][k]
        bf16x8 a0 = *(const bf16x8*)&lA[(wave * 32 + ln) * 40 + q * 8];
        bf16x8 a1 = *(const bf16x8*)&lA[(wave * 32 + 16 + ln) * 40 + q * 8];
        #pragma unroll
        for (int nf = 0; nf < 4; ++nf) {
            bf16x8 b = *(const bf16x8*)&lB[(nf * 16 + ln) * 264 + ks * 32 + q * 8];
            acc[0][nf] = __builtin_amdgcn_mfma_f32_16x16x32_bf16(a0, b, acc[0][nf], 0, 0, 0);
            acc[1][nf] = __builtin_amdgcn_mfma_f32_16x16x32_bf16(a1, b, acc[1][nf], 0, 0, 0);
        }
    }

    // epilogue: D[m = q*4+reg][n = ln] per frag; add head-mean bias
    float bvb[4];
    #pragma unroll
    for (int nf = 0; nf < 4; ++nf) {
        int c = nf * 16 + ln;
        bvb[nf] = 0.25f * (bv[c] + bv[64 + c] + bv[128 + c] + bv[192 + c]);
    }
    #pragma unroll
    for (int mf = 0; mf < 2; ++mf) {
        #pragma unroll
        for (int r4 = 0; r4 < 4; ++r4) {
            int m = wave * 32 + mf * 16 + q * 4 + r4;
            int g = n0 + m;
            if (g < N_NODES) {
                #pragma unroll
                for (int nf = 0; nf < 4; ++nf)
                    vbar[g * 64 + nf * 16 + ln] = acc[mf][nf][r4] + bvb[nf];
            }
        }
    }

    // fp32 column sums of this block's rows (L2-hot re-read) -> ss
    {
        float sum = 0.f;
        #pragma unroll 8
        for (int rr = 0; rr < 128; ++rr) {
            int g = n0 + rr;
            if (g < N_NODES) sum += Xs[g * 256 + t];
        }
        atomicAdd(&ss[t], sum);
    }
}

// ---------------- attention constant: a[d] = 0.25/N * sum_h v_sum[h*64+d]
// v_sum[j] = Wv[j,:].ss + N*bv[j]
__global__ void k_scalar(const float* __restrict__ Wv, const float* __restrict__ bv,
                         const float* __restrict__ ss, float* __restrict__ aout)
{
    __shared__ float dot[256];
    __shared__ float s_ss[256];
    int t = threadIdx.x;
    s_ss[t] = ss[t];
    __syncthreads();
    float s = (float)N_NODES * bv[t];
    #pragma unroll 8
    for (int c = 0; c < 256; ++c) s += Wv[t * 256 + c] * s_ss[c];
    dot[t] = s;
    __syncthreads();
    if (t < 64) {
        aout[t] = 0.25f * (dot[t] + dot[64 + t] + dot[128 + t] + dot[192 + t])
                  / (float)N_NODES;
    }
}

// ---------------- GCN gather: one wave per node, lane = d-channel ----------------
// out[n,d] = aconst[d] + sum_{e in [off[n],off[n+1])} srt[e].val * vbar[srt[e].row, d]
__global__ __launch_bounds__(256) void k_gather(
    const int* __restrict__ off, const float2* __restrict__ srt,
    const float* __restrict__ vbar, const float* __restrict__ aout,
    float* __restrict__ out)
{
    const int t = threadIdx.x;
    const int lane = t & 63;
    const int n = blockIdx.x * 4 + (t >> 6);          // grid sized exactly N/4
    const int e0 = off[n];
    const int e1 = off[n + 1];
    float acc = 0.f;
    int e = e0;
    // unroll-by-2 main loop
    for (; e + 1 < e1; e += 2) {
        float2 rv0 = srt[e];
        float2 rv1 = srt[e + 1];
        int r0 = __float_as_int(rv0.x);
        int r1 = __float_as_int(rv1.x);
        acc += rv0.y * vbar[r0 * 64 + lane];
        acc += rv1.y * vbar[r1 * 64 + lane];
    }
    if (e < e1) {
        float2 rv = srt[e];
        int r = __float_as_int(rv.x);
        acc += rv.y * vbar[r * 64 + lane];
    }
    out[n * 64 + lane] = acc + aout[lane];
}

extern "C" void kernel_launch(void* const* d_in, const int* in_sizes, int n_in,
                              void* d_out, int out_size, void* d_ws, size_t ws_size,
                              hipStream_t stream)
{
    const float* Xs = (const float*)d_in[1];   // source_input [N,256]
    const float* Wv = (const float*)d_in[6];   // Wv_w [256,256]
    const float* bv = (const float*)d_in[7];   // Wv_b [256]
    const int*   ei = (const int*)d_in[8];     // edge_index [2,E]
    const float* ew = (const float*)d_in[9];   // edge_weight [E]
    float* out = (float*)d_out;                // [N,64]

    float*  vbar   = (float*)d_ws;                              // 3.2M floats (12.8 MB)
    float2* srt    = (float2*)(vbar + (size_t)N_NODES * 64);    // 800K float2 (6.4 MB)
    int*    deg    = (int*)(srt + N_EDGES);                     // 50000
    int*    off    = deg + N_NODES;                             // 50001
    int*    cursor = off + N_NODES + 1;                         // 50000
    int*    bsum   = cursor + N_NODES;                          // 196
    int*    boff   = bsum + NB;                                 // 196
    float*  ss     = (float*)(boff + NB);                       // 256
    float*  aout   = ss + 256;                                  // 64

    // zero deg + ss (off/cursor/bsum/boff/aout are fully written by kernels)
    hipMemsetAsync(deg, 0, (size_t)(3 * N_NODES + 1 + 2 * NB + 256 + 64) * 4, stream);
    k_deg<<<N_EDGES / 256, 256, 0, stream>>>(ei, deg);
    k_vbar<<<(N_NODES + 127) / 128, 256, 0, stream>>>(Xs, Wv, bv, vbar, ss);
    k_bsum<<<NB, 256, 0, stream>>>(deg, bsum);
    k_bscan<<<1, 256, 0, stream>>>(bsum, boff);
    k_off<<<NB, 256, 0, stream>>>(deg, boff, off, cursor);
    k_sort<<<N_EDGES / 256, 256, 0, stream>>>(ei, ew, deg, cursor, srt);
    k_scalar<<<1, 256, 0, stream>>>(Wv, bv, ss, aout);
    k_gather<<<(N_NODES + 3) / 4, 256, 0, stream>>>(off, srt, vbar, aout, out);
}

// Round 4
// 280.081 us; speedup vs baseline: 3.2959x; 1.2126x over previous
//
#include <hip/hip_runtime.h>
#include <hip/hip_bf16.h>

#define N_NODES 50000
#define N_EDGES 800000
#define NB 196              // scan blocks: 196*256 = 50176 >= N_NODES

typedef __bf16 bf16x8 __attribute__((ext_vector_type(8)));
typedef float f32x4 __attribute__((ext_vector_type(4)));

__device__ __forceinline__ unsigned short f2bf(float f) {
    unsigned int u = __builtin_bit_cast(unsigned int, f);
    u += 0x7fffu + ((u >> 16) & 1u);   // round-to-nearest-even
    return (unsigned short)(u >> 16);
}

// ---------------- degree count: deg[col] += 1 ----------------
__global__ void k_deg(const int* __restrict__ ei, int* __restrict__ deg) {
    int e = blockIdx.x * 256 + threadIdx.x;           // grid sized exactly E
    atomicAdd(&deg[ei[N_EDGES + e]], 1);
}

// ---------------- Wvbar prep: head-averaged Wv -> bf16 [64][256]; bvbar[64] ----
__global__ __launch_bounds__(256) void k_wprep(const float* __restrict__ Wv,
                                               const float* __restrict__ bv,
                                               unsigned short* __restrict__ wvbar,
                                               float* __restrict__ bvbar) {
    int idx = blockIdx.x * 256 + threadIdx.x;   // 16 blocks -> 4096, 4 cols each
    int d = idx >> 6;
    int c = (idx & 63) * 4;
    const float4* W4 = (const float4*)Wv;
    float4 w0 = W4[((d) * 256 + c) >> 2];
    float4 w1 = W4[((64 + d) * 256 + c) >> 2];
    float4 w2 = W4[((128 + d) * 256 + c) >> 2];
    float4 w3 = W4[((192 + d) * 256 + c) >> 2];
    ushort4 s;
    s.x = f2bf(0.25f * (w0.x + w1.x + w2.x + w3.x));
    s.y = f2bf(0.25f * (w0.y + w1.y + w2.y + w3.y));
    s.z = f2bf(0.25f * (w0.z + w1.z + w2.z + w3.z));
    s.w = f2bf(0.25f * (w0.w + w1.w + w2.w + w3.w));
    *(ushort4*)&wvbar[idx * 4] = s;
    if (blockIdx.x == 0 && threadIdx.x < 64) {
        int t = threadIdx.x;
        bvbar[t] = 0.25f * (bv[t] + bv[64 + t] + bv[128 + t] + bv[192 + t]);
    }
}

// ---------------- scan stage 1: per-block sums of deg ----------------
__global__ __launch_bounds__(256) void k_bsum(const int* __restrict__ deg,
                                              int* __restrict__ bsum) {
    __shared__ int ws[4];
    int t = threadIdx.x;
    int g = blockIdx.x * 256 + t;
    int v = (g < N_NODES) ? deg[g] : 0;
    #pragma unroll
    for (int d = 32; d > 0; d >>= 1) v += __shfl_down(v, d, 64);
    if ((t & 63) == 0) ws[t >> 6] = v;
    __syncthreads();
    if (t == 0) bsum[blockIdx.x] = ws[0] + ws[1] + ws[2] + ws[3];
}

// ---------------- scan stage 2: exclusive scan of 196 block sums ----------------
__global__ __launch_bounds__(256) void k_bscan(const int* __restrict__ bsum,
                                               int* __restrict__ boff) {
    __shared__ int s[256];
    int t = threadIdx.x;
    s[t] = (t < NB) ? bsum[t] : 0;
    __syncthreads();
    #pragma unroll
    for (int d = 1; d < 256; d <<= 1) {
        int v = (t >= d) ? s[t - d] : 0;
        __syncthreads();
        if (t >= d) s[t] += v;
        __syncthreads();
    }
    if (t < NB) boff[t] = (t == 0) ? 0 : s[t - 1];
}

// ---------------- scan stage 3: intra-block scan + block offset -> off/cursor ----
__global__ __launch_bounds__(256) void k_off(const int* __restrict__ deg,
                                             const int* __restrict__ boff,
                                             int* __restrict__ off,
                                             int* __restrict__ cursor) {
    __shared__ int s[256];
    int t = threadIdx.x;
    int g = blockIdx.x * 256 + t;
    int d0 = (g < N_NODES) ? deg[g] : 0;
    s[t] = d0;
    __syncthreads();
    #pragma unroll
    for (int d = 1; d < 256; d <<= 1) {
        int v = (t >= d) ? s[t - d] : 0;
        __syncthreads();
        if (t >= d) s[t] += v;
        __syncthreads();
    }
    int excl = boff[blockIdx.x] + ((t == 0) ? 0 : s[t - 1]);
    if (g < N_NODES) { off[g] = excl; cursor[g] = excl; }
    if (g == 0) off[N_NODES] = N_EDGES;   // sum(deg) == E by construction
}

// ---------------- counting sort by col: srt[pos] = (row, val) ----------------
__global__ void k_sort(const int* __restrict__ ei, const float* __restrict__ ew,
                       const int* __restrict__ deg, int* __restrict__ cursor,
                       float2* __restrict__ srt)
{
    int e = blockIdx.x * 256 + threadIdx.x;           // grid sized exactly E
    int row = ei[e];
    int col = ei[N_EDGES + e];
    float w = ew[e];
    int dr = deg[row];
    int dc = deg[col];
    float val = 0.f;
    if (dr > 0) val = w * rsqrtf((float)dr * (float)dc);  // deg[row]==0 -> nan_to_num -> 0
    int pos = atomicAdd(&cursor[col], 1);
    float2 rv;
    rv.x = __int_as_float(row);
    rv.y = val;
    srt[pos] = rv;
}

// ---------------- vbar GEMM (64-row tiles, full-K, single stage) ----------------
// vbar[n,d] = sum_c Xs[n,c]*Wvbar[d,c] + bvbar[d]; vsumcol[d] += sum_n acc (pre-bias)
__global__ __launch_bounds__(256, 2) void k_vbar(
    const float* __restrict__ Xs, const unsigned short* __restrict__ wvbar,
    const float* __restrict__ bvbar, float* __restrict__ vbar,
    float* __restrict__ vsumcol)
{
    __shared__ unsigned short lA[64 * 264];   // 64 rows x 256 k, stride 264 (pad)
    __shared__ unsigned short lB[64 * 264];   // 64 d-rows x 256 k, stride 264 (pad)
    __shared__ float lvs[64];
    const int t = threadIdx.x;
    const int n0 = blockIdx.x * 64;
    const int w = t >> 6;
    const int ln = t & 15;
    const int q = (t & 63) >> 4;

    if (t < 64) lvs[t] = 0.f;

    // --- B: load precomputed Wvbar bf16 (L2-hot), 8 x uint4 per thread ---
    {
        const uint4* Wb = (const uint4*)wvbar;
        #pragma unroll
        for (int j = 0; j < 8; ++j) {
            int g = j * 256 + t;              // uint4 index: d = g>>5, cblk = g&31
            uint4 u = Wb[g];
            *(uint4*)&lB[(g >> 5) * 264 + (g & 31) * 8] = u;
        }
    }

    // --- A: stage 64 rows x 256 cols fp32 -> bf16, 16 float4 per thread ---
    {
        const int r = t >> 2;                 // row within tile
        const int cblk = (t & 3) * 16;        // float4 block base
        const int g = n0 + r;
        const float4* X4 = (const float4*)Xs;
        if (g < N_NODES) {
            #pragma unroll
            for (int i = 0; i < 16; ++i) {
                float4 x = X4[g * 64 + cblk + i];
                ushort4 s;
                s.x = f2bf(x.x); s.y = f2bf(x.y); s.z = f2bf(x.z); s.w = f2bf(x.w);
                *(ushort4*)&lA[r * 264 + (cblk + i) * 4] = s;
            }
        } else {
            #pragma unroll
            for (int i = 0; i < 16; ++i)
                *(ushort4*)&lA[r * 264 + (cblk + i) * 4] = (ushort4){0, 0, 0, 0};
        }
    }
    __syncthreads();

    f32x4 acc[4];
    #pragma unroll
    for (int nf = 0; nf < 4; ++nf) acc[nf] = (f32x4){0.f, 0.f, 0.f, 0.f};

    #pragma unroll
    for (int ks = 0; ks < 8; ++ks) {
        bf16x8 a = *(const bf16x8*)&lA[(w * 16 + ln) * 264 + ks * 32 + q * 8];
        #pragma unroll
        for (int nf = 0; nf < 4; ++nf) {
            bf16x8 b = *(const bf16x8*)&lB[(nf * 16 + ln) * 264 + ks * 32 + q * 8];
            acc[nf] = __builtin_amdgcn_mfma_f32_16x16x32_bf16(a, b, acc[nf], 0, 0, 0);
        }
    }

    // epilogue: D[m = q*4+r4][n = ln]; write vbar (+bias), reduce column sums
    #pragma unroll
    for (int nf = 0; nf < 4; ++nf) {
        float bvb = bvbar[nf * 16 + ln];
        float p = 0.f;
        #pragma unroll
        for (int r4 = 0; r4 < 4; ++r4) {
            int g = n0 + w * 16 + q * 4 + r4;
            if (g < N_NODES)
                vbar[g * 64 + nf * 16 + ln] = acc[nf][r4] + bvb;
            p += acc[nf][r4];
        }
        atomicAdd(&lvs[nf * 16 + ln], p);
    }
    __syncthreads();
    if (t < 64) atomicAdd(&vsumcol[t], lvs[t]);
}

// ---------------- GCN gather: one wave per node, lane = d-channel ----------------
// out[n,d] = vsumcol[d]/N + bvbar[d] + sum_e srt[e].val * vbar[srt[e].row, d]
__global__ __launch_bounds__(256) void k_gather(
    const int* __restrict__ off, const float2* __restrict__ srt,
    const float* __restrict__ vbar, const float* __restrict__ vsumcol,
    const float* __restrict__ bvbar, float* __restrict__ out)
{
    const int t = threadIdx.x;
    const int lane = t & 63;
    const int n = blockIdx.x * 4 + (t >> 6);          // grid sized exactly N/4
    const int e0 = off[n];
    const int e1 = off[n + 1];
    float acc = 0.f;
    int e = e0;
    for (; e + 3 < e1; e += 4) {
        float2 rv0 = srt[e];
        float2 rv1 = srt[e + 1];
        float2 rv2 = srt[e + 2];
        float2 rv3 = srt[e + 3];
        float a0 = rv0.y * vbar[__float_as_int(rv0.x) * 64 + lane];
        float a1 = rv1.y * vbar[__float_as_int(rv1.x) * 64 + lane];
        float a2 = rv2.y * vbar[__float_as_int(rv2.x) * 64 + lane];
        float a3 = rv3.y * vbar[__float_as_int(rv3.x) * 64 + lane];
        acc += (a0 + a1) + (a2 + a3);
    }
    for (; e < e1; ++e) {
        float2 rv = srt[e];
        acc += rv.y * vbar[__float_as_int(rv.x) * 64 + lane];
    }
    float aconst = vsumcol[lane] * (1.0f / (float)N_NODES) + bvbar[lane];
    out[n * 64 + lane] = acc + aconst;
}

extern "C" void kernel_launch(void* const* d_in, const int* in_sizes, int n_in,
                              void* d_out, int out_size, void* d_ws, size_t ws_size,
                              hipStream_t stream)
{
    const float* Xs = (const float*)d_in[1];   // source_input [N,256]
    const float* Wv = (const float*)d_in[6];   // Wv_w [256,256]
    const float* bv = (const float*)d_in[7];   // Wv_b [256]
    const int*   ei = (const int*)d_in[8];     // edge_index [2,E]
    const float* ew = (const float*)d_in[9];   // edge_weight [E]
    float* out = (float*)d_out;                // [N,64]

    float*  vbar    = (float*)d_ws;                             // 3,200,000 f
    float2* srt     = (float2*)(vbar + (size_t)N_NODES * 64);   // 800,000 float2
    unsigned short* wvbar = (unsigned short*)(srt + N_EDGES);   // 16,384 bf16 (16B-aligned)
    float*  bvbar   = (float*)(wvbar + 16384);                  // 64
    float*  vsumcol = bvbar + 64;                               // 64
    int*    deg     = (int*)(vsumcol + 64);                     // 50,000
    int*    off     = deg + N_NODES;                            // 50,001
    int*    cursor  = off + N_NODES + 1;                        // 50,000
    int*    bsum    = cursor + N_NODES;                         // 196
    int*    boff    = bsum + NB;                                // 196

    // zero vsumcol + deg (adjacent); off/cursor/bsum/boff/wvbar/bvbar fully written
    hipMemsetAsync(vsumcol, 0, (size_t)(64 + N_NODES) * 4, stream);
    k_deg<<<N_EDGES / 256, 256, 0, stream>>>(ei, deg);
    k_wprep<<<16, 256, 0, stream>>>(Wv, bv, wvbar, bvbar);
    k_vbar<<<(N_NODES + 63) / 64, 256, 0, stream>>>(Xs, wvbar, bvbar, vbar, vsumcol);
    k_bsum<<<NB, 256, 0, stream>>>(deg, bsum);
    k_bscan<<<1, 256, 0, stream>>>(bsum, boff);
    k_off<<<NB, 256, 0, stream>>>(deg, boff, off, cursor);
    k_sort<<<N_EDGES / 256, 256, 0, stream>>>(ei, ew, deg, cursor, srt);
    k_gather<<<(N_NODES + 3) / 4, 256, 0, stream>>>(off, srt, vbar, vsumcol, bvbar, out);
}

// Round 5
// 274.442 us; speedup vs baseline: 3.3636x; 1.0205x over previous
//
#include <hip/hip_runtime.h>
#include <hip/hip_bf16.h>

#define N_NODES 50000
#define N_EDGES 800000
#define NB 196              // scan blocks: 196*256 = 50176 >= N_NODES

typedef __bf16 bf16x8 __attribute__((ext_vector_type(8)));
typedef float f32x4 __attribute__((ext_vector_type(4)));

__device__ __forceinline__ unsigned short f2bf(float f) {
    unsigned int u = __builtin_bit_cast(unsigned int, f);
    u += 0x7fffu + ((u >> 16) & 1u);   // round-to-nearest-even
    return (unsigned short)(u >> 16);
}

// ---------------- degree count: deg[col] += 1 ----------------
__global__ void k_deg(const int* __restrict__ ei, int* __restrict__ deg) {
    int e = blockIdx.x * 256 + threadIdx.x;           // grid sized exactly E
    atomicAdd(&deg[ei[N_EDGES + e]], 1);
}

// ---------------- Wvbar prep: head-averaged Wv -> bf16 [64][256]; bvbar[64] ----
__global__ __launch_bounds__(256) void k_wprep(const float* __restrict__ Wv,
                                               const float* __restrict__ bv,
                                               unsigned short* __restrict__ wvbar,
                                               float* __restrict__ bvbar) {
    int idx = blockIdx.x * 256 + threadIdx.x;   // 16 blocks -> 4096, 4 cols each
    int d = idx >> 6;
    int c = (idx & 63) * 4;
    const float4* W4 = (const float4*)Wv;
    float4 w0 = W4[((d) * 256 + c) >> 2];
    float4 w1 = W4[((64 + d) * 256 + c) >> 2];
    float4 w2 = W4[((128 + d) * 256 + c) >> 2];
    float4 w3 = W4[((192 + d) * 256 + c) >> 2];
    ushort4 s;
    s.x = f2bf(0.25f * (w0.x + w1.x + w2.x + w3.x));
    s.y = f2bf(0.25f * (w0.y + w1.y + w2.y + w3.y));
    s.z = f2bf(0.25f * (w0.z + w1.z + w2.z + w3.z));
    s.w = f2bf(0.25f * (w0.w + w1.w + w2.w + w3.w));
    *(ushort4*)&wvbar[idx * 4] = s;
    if (blockIdx.x == 0 && threadIdx.x < 64) {
        int t = threadIdx.x;
        bvbar[t] = 0.25f * (bv[t] + bv[64 + t] + bv[128 + t] + bv[192 + t]);
    }
}

// ---------------- scan stage 1: per-block sums of deg ----------------
__global__ __launch_bounds__(256) void k_bsum(const int* __restrict__ deg,
                                              int* __restrict__ bsum) {
    __shared__ int ws[4];
    int t = threadIdx.x;
    int g = blockIdx.x * 256 + t;
    int v = (g < N_NODES) ? deg[g] : 0;
    #pragma unroll
    for (int d = 32; d > 0; d >>= 1) v += __shfl_down(v, d, 64);
    if ((t & 63) == 0) ws[t >> 6] = v;
    __syncthreads();
    if (t == 0) bsum[blockIdx.x] = ws[0] + ws[1] + ws[2] + ws[3];
}

// ---------------- scan stage 2: exclusive scan of 196 block sums ----------------
__global__ __launch_bounds__(256) void k_bscan(const int* __restrict__ bsum,
                                               int* __restrict__ boff) {
    __shared__ int s[256];
    int t = threadIdx.x;
    s[t] = (t < NB) ? bsum[t] : 0;
    __syncthreads();
    #pragma unroll
    for (int d = 1; d < 256; d <<= 1) {
        int v = (t >= d) ? s[t - d] : 0;
        __syncthreads();
        if (t >= d) s[t] += v;
        __syncthreads();
    }
    if (t < NB) boff[t] = (t == 0) ? 0 : s[t - 1];
}

// ---------------- scan stage 3: intra-block scan + block offset -> off/cursor ----
__global__ __launch_bounds__(256) void k_off(const int* __restrict__ deg,
                                             const int* __restrict__ boff,
                                             int* __restrict__ off,
                                             int* __restrict__ cursor) {
    __shared__ int s[256];
    int t = threadIdx.x;
    int g = blockIdx.x * 256 + t;
    int d0 = (g < N_NODES) ? deg[g] : 0;
    s[t] = d0;
    __syncthreads();
    #pragma unroll
    for (int d = 1; d < 256; d <<= 1) {
        int v = (t >= d) ? s[t - d] : 0;
        __syncthreads();
        if (t >= d) s[t] += v;
        __syncthreads();
    }
    int excl = boff[blockIdx.x] + ((t == 0) ? 0 : s[t - 1]);
    if (g < N_NODES) { off[g] = excl; cursor[g] = excl; }
    if (g == 0) off[N_NODES] = N_EDGES;   // sum(deg) == E by construction
}

// ---------------- counting sort by col: srt[pos] = (row<<16 | bf16(val)) -------
__global__ void k_sort(const int* __restrict__ ei, const float* __restrict__ ew,
                       const int* __restrict__ deg, int* __restrict__ cursor,
                       unsigned int* __restrict__ srt)
{
    int e = blockIdx.x * 256 + threadIdx.x;           // grid sized exactly E
    int row = ei[e];
    int col = ei[N_EDGES + e];
    float w = ew[e];
    int dr = deg[row];
    int dc = deg[col];
    float val = 0.f;
    if (dr > 0) val = w * rsqrtf((float)dr * (float)dc);  // deg[row]==0 -> nan_to_num -> 0
    int pos = atomicAdd(&cursor[col], 1);
    unsigned int packed = ((unsigned int)row << 16) | (unsigned int)f2bf(val);
    srt[pos] = packed;
}

// ---------------- vbar GEMM (64-row tiles, full-K, single stage) ----------------
// vbar[n,d] = sum_c Xs[n,c]*Wvbar[d,c] + bvbar[d]; vsumcol[d] += sum_n acc (pre-bias)
__global__ __launch_bounds__(256, 2) void k_vbar(
    const float* __restrict__ Xs, const unsigned short* __restrict__ wvbar,
    const float* __restrict__ bvbar, float* __restrict__ vbar,
    float* __restrict__ vsumcol)
{
    __shared__ unsigned short lA[64 * 264];   // 64 rows x 256 k, stride 264 (pad)
    __shared__ unsigned short lB[64 * 264];   // 64 d-rows x 256 k, stride 264 (pad)
    __shared__ float lvs[64];
    const int t = threadIdx.x;
    const int n0 = blockIdx.x * 64;
    const int w = t >> 6;
    const int ln = t & 15;
    const int q = (t & 63) >> 4;

    if (t < 64) lvs[t] = 0.f;

    // --- B: load precomputed Wvbar bf16 (L2-hot), 8 x uint4 per thread ---
    {
        const uint4* Wb = (const uint4*)wvbar;
        #pragma unroll
        for (int j = 0; j < 8; ++j) {
            int g = j * 256 + t;              // uint4 index: d = g>>5, cblk = g&31
            uint4 u = Wb[g];
            *(uint4*)&lB[(g >> 5) * 264 + (g & 31) * 8] = u;
        }
    }

    // --- A: stage 64 rows x 256 cols fp32 -> bf16, 16 float4 per thread ---
    {
        const int r = t >> 2;                 // row within tile
        const int cblk = (t & 3) * 16;        // float4 block base
        const int g = n0 + r;
        const float4* X4 = (const float4*)Xs;
        if (g < N_NODES) {
            #pragma unroll
            for (int i = 0; i < 16; ++i) {
                float4 x = X4[g * 64 + cblk + i];
                ushort4 s;
                s.x = f2bf(x.x); s.y = f2bf(x.y); s.z = f2bf(x.z); s.w = f2bf(x.w);
                *(ushort4*)&lA[r * 264 + (cblk + i) * 4] = s;
            }
        } else {
            #pragma unroll
            for (int i = 0; i < 16; ++i)
                *(ushort4*)&lA[r * 264 + (cblk + i) * 4] = (ushort4){0, 0, 0, 0};
        }
    }
    __syncthreads();

    f32x4 acc[4];
    #pragma unroll
    for (int nf = 0; nf < 4; ++nf) acc[nf] = (f32x4){0.f, 0.f, 0.f, 0.f};

    #pragma unroll
    for (int ks = 0; ks < 8; ++ks) {
        bf16x8 a = *(const bf16x8*)&lA[(w * 16 + ln) * 264 + ks * 32 + q * 8];
        #pragma unroll
        for (int nf = 0; nf < 4; ++nf) {
            bf16x8 b = *(const bf16x8*)&lB[(nf * 16 + ln) * 264 + ks * 32 + q * 8];
            acc[nf] = __builtin_amdgcn_mfma_f32_16x16x32_bf16(a, b, acc[nf], 0, 0, 0);
        }
    }

    // epilogue: D[m = q*4+r4][n = ln]; write vbar (+bias), reduce column sums
    #pragma unroll
    for (int nf = 0; nf < 4; ++nf) {
        float bvb = bvbar[nf * 16 + ln];
        float p = 0.f;
        #pragma unroll
        for (int r4 = 0; r4 < 4; ++r4) {
            int g = n0 + w * 16 + q * 4 + r4;
            if (g < N_NODES)
                vbar[g * 64 + nf * 16 + ln] = acc[nf][r4] + bvb;
            p += acc[nf][r4];
        }
        atomicAdd(&lvs[nf * 16 + ln], p);
    }
    __syncthreads();
    if (t < 64) atomicAdd(&vsumcol[t], lvs[t]);
}

// ---------------- GCN gather: one wave per node, lane = d-channel ----------------
// out[n,d] = vsumcol[d]/N + bvbar[d] + sum_e val_e * vbar[row_e, d]
__global__ __launch_bounds__(256) void k_gather(
    const int* __restrict__ off, const unsigned int* __restrict__ srt,
    const float* __restrict__ vbar, const float* __restrict__ vsumcol,
    const float* __restrict__ bvbar, float* __restrict__ out)
{
    const int t = threadIdx.x;
    const int lane = t & 63;
    const int n = blockIdx.x * 4 + (t >> 6);          // grid sized exactly N/4
    const int e0 = off[n];
    const int e1 = off[n + 1];
    float acc = 0.f;
    int e = e0;
    for (; e + 3 < e1; e += 4) {
        unsigned int p0 = srt[e];
        unsigned int p1 = srt[e + 1];
        unsigned int p2 = srt[e + 2];
        unsigned int p3 = srt[e + 3];
        float v0 = __uint_as_float(p0 << 16);
        float v1 = __uint_as_float(p1 << 16);
        float v2 = __uint_as_float(p2 << 16);
        float v3 = __uint_as_float(p3 << 16);
        float a0 = v0 * vbar[(p0 >> 16) * 64 + lane];
        float a1 = v1 * vbar[(p1 >> 16) * 64 + lane];
        float a2 = v2 * vbar[(p2 >> 16) * 64 + lane];
        float a3 = v3 * vbar[(p3 >> 16) * 64 + lane];
        acc += (a0 + a1) + (a2 + a3);
    }
    for (; e < e1; ++e) {
        unsigned int p = srt[e];
        acc += __uint_as_float(p << 16) * vbar[(p >> 16) * 64 + lane];
    }
    float aconst = vsumcol[lane] * (1.0f / (float)N_NODES) + bvbar[lane];
    out[n * 64 + lane] = acc + aconst;
}

extern "C" void kernel_launch(void* const* d_in, const int* in_sizes, int n_in,
                              void* d_out, int out_size, void* d_ws, size_t ws_size,
                              hipStream_t stream)
{
    const float* Xs = (const float*)d_in[1];   // source_input [N,256]
    const float* Wv = (const float*)d_in[6];   // Wv_w [256,256]
    const float* bv = (const float*)d_in[7];   // Wv_b [256]
    const int*   ei = (const int*)d_in[8];     // edge_index [2,E]
    const float* ew = (const float*)d_in[9];   // edge_weight [E]
    float* out = (float*)d_out;                // [N,64]

    float*  vbar    = (float*)d_ws;                             // 3,200,000 f
    unsigned int* srt = (unsigned int*)(vbar + (size_t)N_NODES * 64); // 800,000 u32
    unsigned short* wvbar = (unsigned short*)(srt + N_EDGES);   // 16,384 bf16 (16B-aligned)
    float*  bvbar   = (float*)(wvbar + 16384);                  // 64
    float*  vsumcol = bvbar + 64;                               // 64
    int*    deg     = (int*)(vsumcol + 64);                     // 50,000
    int*    off     = deg + N_NODES;                            // 50,001
    int*    cursor  = off + N_NODES + 1;                        // 50,000
    int*    bsum    = cursor + N_NODES;                         // 196
    int*    boff    = bsum + NB;                                // 196

    // zero vsumcol + deg (adjacent); off/cursor/bsum/boff/wvbar/bvbar fully written
    hipMemsetAsync(vsumcol, 0, (size_t)(64 + N_NODES) * 4, stream);
    k_deg<<<N_EDGES / 256, 256, 0, stream>>>(ei, deg);
    k_wprep<<<16, 256, 0, stream>>>(Wv, bv, wvbar, bvbar);
    k_vbar<<<(N_NODES + 63) / 64, 256, 0, stream>>>(Xs, wvbar, bvbar, vbar, vsumcol);
    k_bsum<<<NB, 256, 0, stream>>>(deg, bsum);
    k_bscan<<<1, 256, 0, stream>>>(bsum, boff);
    k_off<<<NB, 256, 0, stream>>>(deg, boff, off, cursor);
    k_sort<<<N_EDGES / 256, 256, 0, stream>>>(ei, ew, deg, cursor, srt);
    k_gather<<<(N_NODES + 3) / 4, 256, 0, stream>>>(off, srt, vbar, vsumcol, bvbar, out);
}